// Round 1
// baseline (2615.826 us; speedup 1.0000x reference)
//
#include <hip/hip_runtime.h>
#include <hip/hip_bf16.h>
#include <math.h>

// Problem constants (fixed-size problem)
#define NN   16384   // batch subgraph nodes
#define EE   131072  // edges
#define BB   4096    // events
#define MEMD 256
#define TDW  128
#define MSGD 172
#define GRUIN 812
#define KPAD 816

__device__ __forceinline__ unsigned fkey(float x) {
  unsigned b = __float_as_uint(x);
  return (b & 0x80000000u) ? ~b : (b | 0x80000000u);
}
__device__ __forceinline__ float funkey(unsigned k) {
  unsigned b = (k & 0x80000000u) ? (k & 0x7fffffffu) : ~k;
  return __uint_as_float(b);
}
__device__ __forceinline__ float sigmoidf_(float x) { return 1.f / (1.f + expf(-x)); }

// ---------------------------------------------------------------------------
// Pack q/k/v/skip weights into one [1024,256] matrix + biases; transpose lp_hw.
__global__ void pack_weights(const float* __restrict__ Wq, const float* __restrict__ bq,
                             const float* __restrict__ Wk, const float* __restrict__ bk,
                             const float* __restrict__ Wv, const float* __restrict__ bv,
                             const float* __restrict__ Ws, const float* __restrict__ bs,
                             const float* __restrict__ lp_hw,
                             float* __restrict__ Wcat, float* __restrict__ bcat,
                             float* __restrict__ lpwT) {
  int tid = blockIdx.x * blockDim.x + threadIdx.x; // 0..262143
  {
    int row = tid >> 8, col = tid & 255;
    float v;
    if (row < 256)      v = Wq[row * 256 + col];
    else if (row < 512) v = Wk[(row - 256) * 256 + col];
    else if (row < 768) v = Wv[(row - 512) * 256 + col];
    else                v = Ws[(row - 768) * 256 + col];
    Wcat[tid] = v;
  }
  if (tid < 1024) {
    float v;
    if (tid < 256)      v = bq[tid];
    else if (tid < 512) v = bk[tid - 256];
    else if (tid < 768) v = bv[tid - 512];
    else                v = bs[tid - 768];
    bcat[tid] = v;
  }
  if (tid < 131072) {
    int k = tid >> 8, t = tid & 255;
    lpwT[tid] = lp_hw[t * 512 + k];  // lpwT[k*256+t]
  }
}

// ---------------------------------------------------------------------------
// Per-node: build aggr [NN, KPAD], h [NN,256], lu_f [NN]. One block per node.
__global__ __launch_bounds__(256) void build_node(
    const int* __restrict__ node_ids, const int* __restrict__ mlu,
    const int* __restrict__ mrt, const int* __restrict__ mdst,
    const float* __restrict__ mem_table, const float* __restrict__ mem_msg,
    const float* __restrict__ mdir, const float* __restrict__ tw,
    const float* __restrict__ tb, float* __restrict__ aggr,
    float* __restrict__ h, float* __restrict__ lu_f) {
  int i = blockIdx.x;
  int c = threadIdx.x;  // 0..255
  int nid = node_ids[i];
  int did = mdst[nid];
  float d0 = mdir[nid * 2 + 0], d1 = mdir[nid * 2 + 1];
  float s  = mem_table[(size_t)nid * MEMD + c];
  float dd = mem_table[(size_t)did * MEMD + c];
  size_t base = (size_t)i * KPAD;
  aggr[base + c]       = s * d0 + dd * d1;
  aggr[base + 256 + c] = s * d1 + dd * d0;
  h[(size_t)i * MEMD + c] = s;
  if (c < MSGD) aggr[base + 512 + c] = mem_msg[(size_t)nid * MSGD + c];
  if (c < TDW) {
    float rt = (float)mrt[nid];
    aggr[base + 684 + c] = cosf(rt * tw[c] + tb[c]);
  }
  if (c >= 172 && c < 176) aggr[base + 640 + c] = 0.f;  // zero pad 812..815
  if (c == 0) lu_f[i] = (float)mlu[nid];
}

// rel[e] = lu_f[src[e]] - edge_t[e]
__global__ void edge_rel(const int* __restrict__ src, const float* __restrict__ lu_f,
                         const float* __restrict__ et, float* __restrict__ rel) {
  int e = blockIdx.x * blockDim.x + threadIdx.x;
  if (e < EE) rel[e] = lu_f[src[e]] - et[e];
}

// ---------------------------------------------------------------------------
// C[M,N] = A[M,K] @ B[N,K]^T + bias.  mode 0: A from memory (lda).
// mode 1: virtual A row e = [edge_msg[e,0:172] | cos(rel[e]*tw+tb) (128)]
#define TBM 64
#define TBN 64
#define TBK 16
__global__ __launch_bounds__(256) void gemm_nt(
    const float* __restrict__ A, int lda, const float* __restrict__ B, int ldb,
    const float* __restrict__ bias, float* __restrict__ C, int ldc,
    int Mdim, int Ndim, int Kdim, int mode,
    const float* __restrict__ emsg, const float* __restrict__ rel,
    const float* __restrict__ tw, const float* __restrict__ tb) {
  __shared__ float As[TBK][TBM + 4];
  __shared__ float Bs[TBK][TBN + 4];
  int tid = threadIdx.x;
  int tx = tid & 15, ty = tid >> 4;
  int m0 = blockIdx.x * TBM, n0 = blockIdx.y * TBN;
  float acc[4][4];
#pragma unroll
  for (int i = 0; i < 4; ++i)
#pragma unroll
    for (int j = 0; j < 4; ++j) acc[i][j] = 0.f;

  int lrow = tid >> 2;         // 0..63
  int lk4 = (tid & 3) * 4;     // 0,4,8,12
  int ktiles = (Kdim + TBK - 1) / TBK;
  for (int t = 0; t < ktiles; ++t) {
    int k0 = t * TBK;
#pragma unroll
    for (int j = 0; j < 4; ++j) {
      int k = k0 + lk4 + j;
      int m = m0 + lrow;
      float v = 0.f;
      if (k < Kdim) {
        if (mode == 0) v = A[(size_t)m * lda + k];
        else {
          if (k < MSGD) v = emsg[(size_t)m * MSGD + k];
          else          v = cosf(rel[m] * tw[k - MSGD] + tb[k - MSGD]);
        }
      }
      As[lk4 + j][lrow] = v;
    }
#pragma unroll
    for (int j = 0; j < 4; ++j) {
      int k = k0 + lk4 + j;
      int n = n0 + lrow;
      float v = 0.f;
      if (k < Kdim && n < Ndim) v = B[(size_t)n * ldb + k];
      Bs[lk4 + j][lrow] = v;
    }
    __syncthreads();
#pragma unroll
    for (int k = 0; k < TBK; ++k) {
      float a[4], b[4];
#pragma unroll
      for (int i = 0; i < 4; ++i) a[i] = As[k][ty * 4 + i];
#pragma unroll
      for (int i = 0; i < 4; ++i) b[i] = Bs[k][tx * 4 + i];
#pragma unroll
      for (int i = 0; i < 4; ++i)
#pragma unroll
        for (int j = 0; j < 4; ++j) acc[i][j] += a[i] * b[j];
    }
    __syncthreads();
  }
#pragma unroll
  for (int i = 0; i < 4; ++i) {
    int m = m0 + ty * 4 + i;
#pragma unroll
    for (int j = 0; j < 4; ++j) {
      int n = n0 + tx * 4 + j;
      float v = acc[i][j] + (bias ? bias[n] : 0.f);
      C[(size_t)m * ldc + n] = v;
    }
  }
}

// ---------------------------------------------------------------------------
// GRU combine: memory = (1-z)*tanh(i_n + r*h_n) + z*h
__global__ void gru_combine(const float* __restrict__ gi, const float* __restrict__ gh,
                            const float* __restrict__ h, float* __restrict__ mem) {
  int idx = blockIdx.x * blockDim.x + threadIdx.x;  // NN*256
  int n = idx >> 8, c = idx & 255;
  size_t b = (size_t)n * 768;
  float ir = gi[b + c], iz = gi[b + 256 + c], in_ = gi[b + 512 + c];
  float hr = gh[b + c], hz = gh[b + 256 + c], hn = gh[b + 512 + c];
  float r = sigmoidf_(ir + hr);
  float z = sigmoidf_(iz + hz);
  float nn = tanhf(in_ + r * hn);
  float hv = h[idx];
  mem[idx] = (1.f - z) * nn + z * hv;
}

// z init from skip columns of qkvs; zero denom; zero max keys.
__global__ void init_attn(const float* __restrict__ qkvs, float* __restrict__ z,
                          float* __restrict__ denom, unsigned* __restrict__ maxkey) {
  int idx = blockIdx.x * blockDim.x + threadIdx.x;  // NN*256
  int n = idx >> 8, c = idx & 255;
  z[idx] = qkvs[(size_t)n * 1024 + 768 + c];
  if (idx < NN * 2) denom[idx] = 0.f;
  if (idx < 2) maxkey[idx] = 0u;
}

// alpha[e,h] = q[dst]·(k[src]+eproj[e]) per head / sqrt(128); track global max.
__global__ __launch_bounds__(256) void attn_alpha(
    const int* __restrict__ src, const int* __restrict__ dst,
    const float* __restrict__ qkvs, const float* __restrict__ eproj,
    float* __restrict__ alpha, unsigned* __restrict__ maxkey) {
  __shared__ float wmax[4][2];
  int wid = threadIdx.x >> 6, lane = threadIdx.x & 63;
  int e = blockIdx.x * 4 + wid;
  int sE = src[e], dE = dst[e];
  int c = lane * 4;
  float4 qv = *(const float4*)&qkvs[(size_t)dE * 1024 + c];
  float4 kv = *(const float4*)&qkvs[(size_t)sE * 1024 + 256 + c];
  float4 ev = *(const float4*)&eproj[(size_t)e * 256 + c];
  float p = qv.x * (kv.x + ev.x) + qv.y * (kv.y + ev.y) +
            qv.z * (kv.z + ev.z) + qv.w * (kv.w + ev.w);
#pragma unroll
  for (int off = 16; off >= 1; off >>= 1) p += __shfl_xor(p, off);
  float a = p * 0.08838834764831845f;  // 1/sqrt(128)
  if (lane == 0)  { alpha[e * 2 + 0] = a; wmax[wid][0] = a; }
  if (lane == 32) { alpha[e * 2 + 1] = a; wmax[wid][1] = a; }
  __syncthreads();
  if (threadIdx.x < 2) {
    int hh = threadIdx.x;
    float m = fmaxf(fmaxf(wmax[0][hh], wmax[1][hh]), fmaxf(wmax[2][hh], wmax[3][hh]));
    atomicMax(maxkey + hh, fkey(m));
  }
}

// e_exp = exp(alpha - m); denom[dst,h] += e_exp (segment sum)
__global__ void attn_exp(const int* __restrict__ dst, float* __restrict__ alpha,
                         const unsigned* __restrict__ maxkey, float* __restrict__ denom) {
  int idx = blockIdx.x * blockDim.x + threadIdx.x;  // EE*2
  if (idx >= EE * 2) return;
  int e = idx >> 1, hh = idx & 1;
  float m = funkey(maxkey[hh]);
  float v = expf(alpha[idx] - m);
  alpha[idx] = v;
  atomicAdd(&denom[dst[e] * 2 + hh], v);
}

// z[dst] += (v[src]+eproj[e]) * alpha_norm
__global__ __launch_bounds__(256) void attn_agg(
    const int* __restrict__ src, const int* __restrict__ dst,
    const float* __restrict__ qkvs, const float* __restrict__ eproj,
    const float* __restrict__ alpha, const float* __restrict__ denom,
    float* __restrict__ z) {
  int wid = threadIdx.x >> 6, lane = threadIdx.x & 63;
  int e = blockIdx.x * 4 + wid;
  int sE = src[e], dE = dst[e];
  float c0 = alpha[e * 2 + 0] / (denom[dE * 2 + 0] + 1e-16f);
  float c1 = alpha[e * 2 + 1] / (denom[dE * 2 + 1] + 1e-16f);
  int c = lane * 4;
  float coef = (c < 128) ? c0 : c1;
  float4 vv = *(const float4*)&qkvs[(size_t)sE * 1024 + 512 + c];
  float4 ev = *(const float4*)&eproj[(size_t)e * 256 + c];
  float* zp = &z[(size_t)dE * 256 + c];
  atomicAdd(zp + 0, (vv.x + ev.x) * coef);
  atomicAdd(zp + 1, (vv.y + ev.y) * coef);
  atomicAdd(zp + 2, (vv.z + ev.z) * coef);
  atomicAdd(zp + 3, (vv.w + ev.w) * coef);
}

// ---------------------------------------------------------------------------
// LinkPredictor: 16 rows per block. hidden t = thread t; reduce over threads.
__global__ __launch_bounds__(256) void link_pred_k(
    const int* __restrict__ node_idx, const float* __restrict__ z,
    const float* __restrict__ lpwT, const float* __restrict__ lp_hb,
    const float* __restrict__ lp_fw, const float* __restrict__ lp_fb,
    float* __restrict__ out) {
  __shared__ float cat[16][512];
  __shared__ float red[16][4];
  __shared__ int i0s[16];
  int tid = threadIdx.x;
#pragma unroll
  for (int rr = 0; rr < 16; ++rr) {
    int row = blockIdx.x * 16 + rr;     // 0..8191
    int b = row & (BB - 1);
    int neg = row >= BB;
    int i0 = node_idx[b];
    int i1 = node_idx[(neg ? 2 : 1) * BB + b];
    if (tid == 0) i0s[rr] = i0;
    cat[rr][tid]       = z[(size_t)i0 * 256 + tid];
    cat[rr][256 + tid] = z[(size_t)i1 * 256 + tid];
  }
  __syncthreads();
  float acc[16];
#pragma unroll
  for (int rr = 0; rr < 16; ++rr) acc[rr] = 0.f;
  for (int k = 0; k < 512; ++k) {
    float w = lpwT[k * 256 + tid];
#pragma unroll
    for (int rr = 0; rr < 16; ++rr) acc[rr] += w * cat[rr][k];
  }
  float hb = lp_hb[tid], fw = lp_fw[tid];
  int wid = tid >> 6, lane = tid & 63;
#pragma unroll
  for (int rr = 0; rr < 16; ++rr) {
    float v = fmaxf(acc[rr] + hb, 0.f) * fw;
#pragma unroll
    for (int off = 32; off >= 1; off >>= 1) v += __shfl_xor(v, off);
    if (lane == 0) red[rr][wid] = v;
  }
  __syncthreads();
  if (tid < 16) {
    int rr = tid;
    float dot = red[rr][0] + red[rr][1] + red[rr][2] + red[rr][3] + lp_fb[0];
    float mask = (i0s[rr] < NN - 1) ? 1.f : 0.f;
    out[blockIdx.x * 16 + rr] = sigmoidf_(dot * mask);
  }
}

// ---------------------------------------------------------------------------
extern "C" void kernel_launch(void* const* d_in, const int* in_sizes, int n_in,
                              void* d_out, int out_size, void* d_ws, size_t ws_size,
                              hipStream_t stream) {
  const int* node_ids = (const int*)d_in[0];
  const int* node_idx = (const int*)d_in[1];
  const int* edge_src = (const int*)d_in[2];
  const int* edge_dst = edge_src + EE;
  const int* mlu = (const int*)d_in[3];
  const int* mrt = (const int*)d_in[4];
  const int* mdst = (const int*)d_in[5];
  const float* edge_t = (const float*)d_in[6];
  const float* edge_msg = (const float*)d_in[7];
  const float* mem_table = (const float*)d_in[8];
  const float* mem_msg = (const float*)d_in[9];
  const float* mem_dir = (const float*)d_in[10];
  const float* te_mem_w = (const float*)d_in[11];
  const float* te_mem_b = (const float*)d_in[12];
  const float* gru_w_ih = (const float*)d_in[13];
  const float* gru_w_hh = (const float*)d_in[14];
  const float* gru_b_ih = (const float*)d_in[15];
  const float* gru_b_hh = (const float*)d_in[16];
  const float* te_gnn_w = (const float*)d_in[17];
  const float* te_gnn_b = (const float*)d_in[18];
  const float* Wq = (const float*)d_in[19];  const float* bq = (const float*)d_in[20];
  const float* Wk = (const float*)d_in[21];  const float* bk = (const float*)d_in[22];
  const float* Wv = (const float*)d_in[23];  const float* bv = (const float*)d_in[24];
  const float* We = (const float*)d_in[25];
  const float* Wskip = (const float*)d_in[26]; const float* bskip = (const float*)d_in[27];
  const float* lp_hw = (const float*)d_in[28]; const float* lp_hb = (const float*)d_in[29];
  const float* lp_fw = (const float*)d_in[30]; const float* lp_fb = (const float*)d_in[31];

  float* W = (float*)d_ws;
  // Pool (aliased): aggr/gi/gh then eproj
  float* aggr = W;                              // NN*KPAD   = 13,369,344
  float* gi   = W + 13369344;                   // NN*768    = 12,582,912
  float* gh   = W + 25952256;                   // NN*768    = 12,582,912
  float* eproj = W;                             // EE*256    = 33,554,432 (alias, used after combine)
  float* hbuf = W + 38535168;                   // NN*256
  float* mem  = hbuf + 4194304;                 // NN*256
  float* lu_f = mem + 4194304;                  // NN
  float* rel  = lu_f + NN;                      // EE
  float* Wcat = rel + EE;                       // 1024*256
  float* bcat = Wcat + 262144;                  // 1024
  float* lpwT = bcat + 1024;                    // 512*256
  float* qkvs = lpwT + 131072;                  // NN*1024
  float* alpha = qkvs + 16777216;               // EE*2
  float* denom = alpha + 262144;                // NN*2
  unsigned* maxkey = (unsigned*)(denom + 32768);// 2 (+pad)
  float* zbuf = denom + 32768 + 8;              // NN*256

  pack_weights<<<1024, 256, 0, stream>>>(Wq, bq, Wk, bk, Wv, bv, Wskip, bskip,
                                         lp_hw, Wcat, bcat, lpwT);
  build_node<<<NN, 256, 0, stream>>>(node_ids, mlu, mrt, mdst, mem_table, mem_msg,
                                     mem_dir, te_mem_w, te_mem_b, aggr, hbuf, lu_f);
  edge_rel<<<EE / 256, 256, 0, stream>>>(edge_src, lu_f, edge_t, rel);

  dim3 g1(NN / TBM, 768 / TBN);
  gemm_nt<<<g1, 256, 0, stream>>>(aggr, KPAD, gru_w_ih, GRUIN, gru_b_ih, gi, 768,
                                  NN, 768, GRUIN, 0, nullptr, nullptr, nullptr, nullptr);
  gemm_nt<<<g1, 256, 0, stream>>>(hbuf, 256, gru_w_hh, 256, gru_b_hh, gh, 768,
                                  NN, 768, 256, 0, nullptr, nullptr, nullptr, nullptr);
  gru_combine<<<NN, 256, 0, stream>>>(gi, gh, hbuf, mem);

  dim3 g2(NN / TBM, 1024 / TBN);
  gemm_nt<<<g2, 256, 0, stream>>>(mem, 256, Wcat, 256, bcat, qkvs, 1024,
                                  NN, 1024, 256, 0, nullptr, nullptr, nullptr, nullptr);
  init_attn<<<NN, 256, 0, stream>>>(qkvs, zbuf, denom, maxkey);

  dim3 g3(EE / TBM, 256 / TBN);
  gemm_nt<<<g3, 256, 0, stream>>>(nullptr, 0, We, 300, nullptr, eproj, 256,
                                  EE, 256, 300, 1, edge_msg, rel, te_gnn_w, te_gnn_b);

  attn_alpha<<<EE / 4, 256, 0, stream>>>(edge_src, edge_dst, qkvs, eproj, alpha, maxkey);
  attn_exp<<<(EE * 2) / 256, 256, 0, stream>>>(edge_dst, alpha, maxkey, denom);
  attn_agg<<<EE / 4, 256, 0, stream>>>(edge_src, edge_dst, qkvs, eproj, alpha, denom, zbuf);

  link_pred_k<<<(2 * BB) / 16, 256, 0, stream>>>(node_idx, zbuf, lpwT, lp_hb,
                                                 lp_fw, lp_fb, (float*)d_out);
}

// Round 3
// 1497.127 us; speedup vs baseline: 1.7472x; 1.7472x over previous
//
#include <hip/hip_runtime.h>
#include <hip/hip_bf16.h>
#include <math.h>

// Problem constants
#define NN   16384   // batch subgraph nodes
#define EE   131072  // edges
#define BB   4096    // events
#define MSGD 172
#define KP_AGGR 832  // 812 padded to 26*32
#define KP_EDGE 320  // 300 padded to 10*32

typedef __attribute__((ext_vector_type(8))) short bf16x8;
typedef __attribute__((ext_vector_type(4))) float f32x4;

__device__ __forceinline__ ushort f2b(float x) {
  unsigned u = __float_as_uint(x);
  return (ushort)((u + 0x7fffu + ((u >> 16) & 1u)) >> 16);  // RNE
}
__device__ __forceinline__ float b2f(ushort b) {
  return __uint_as_float(((unsigned)b) << 16);
}
__device__ __forceinline__ unsigned fkey(float x) {
  unsigned b = __float_as_uint(x);
  return (b & 0x80000000u) ? ~b : (b | 0x80000000u);
}
__device__ __forceinline__ float funkey(unsigned k) {
  unsigned b = (k & 0x80000000u) ? (k & 0x7fffffffu) : ~k;
  return __uint_as_float(b);
}
__device__ __forceinline__ float sigmoidf_(float x) { return 1.f / (1.f + expf(-x)); }

// ---------------------------------------------------------------------------
// Weight packing (fp32 -> bf16, padded)
__global__ void pack_gru(const float* __restrict__ w_ih, const float* __restrict__ w_hh,
                         ushort* __restrict__ wihb, ushort* __restrict__ whhb) {
  int n = blockIdx.x;     // 0..767
  int c = threadIdx.x;    // 0..255
  for (int k = c; k < KP_AGGR; k += 256)
    wihb[(size_t)n * KP_AGGR + k] = (k < 812) ? f2b(w_ih[(size_t)n * 812 + k]) : (ushort)0;
  whhb[(size_t)n * 256 + c] = f2b(w_hh[(size_t)n * 256 + c]);
}

__global__ void pack_attn(const float* __restrict__ Wq, const float* __restrict__ bq,
                          const float* __restrict__ Wk, const float* __restrict__ bk,
                          const float* __restrict__ Wv, const float* __restrict__ bv,
                          const float* __restrict__ Ws, const float* __restrict__ bs,
                          const float* __restrict__ We,
                          ushort* __restrict__ wcatb, float* __restrict__ bcat,
                          ushort* __restrict__ web) {
  int n = blockIdx.x;     // 0..1023
  int c = threadIdx.x;    // 0..255
  const float* Wsel; const float* bsel; int r;
  if (n < 256)      { Wsel = Wq; bsel = bq; r = n; }
  else if (n < 512) { Wsel = Wk; bsel = bk; r = n - 256; }
  else if (n < 768) { Wsel = Wv; bsel = bv; r = n - 512; }
  else              { Wsel = Ws; bsel = bs; r = n - 768; }
  wcatb[(size_t)n * 256 + c] = f2b(Wsel[(size_t)r * 256 + c]);
  if (c == 0) bcat[n] = bsel[r];
  if (n < 256) {
    for (int k = c; k < KP_EDGE; k += 256)
      web[(size_t)n * KP_EDGE + k] = (k < 300) ? f2b(We[(size_t)n * 300 + k]) : (ushort)0;
  }
}

__global__ void pack_lp(const float* __restrict__ lp_hw, float* __restrict__ lpwT) {
  int k = blockIdx.x;     // 0..511
  int t = threadIdx.x;    // 0..255
  lpwT[(size_t)k * 256 + t] = lp_hw[(size_t)t * 512 + k];
}

// ---------------------------------------------------------------------------
// Per-node: aggr bf16 [NN, 832], h bf16 [NN,256], lu_f [NN]
__global__ __launch_bounds__(256) void build_node(
    const int* __restrict__ node_ids, const int* __restrict__ mlu,
    const int* __restrict__ mrt, const int* __restrict__ mdst,
    const float* __restrict__ mem_table, const float* __restrict__ mem_msg,
    const float* __restrict__ mdir, const float* __restrict__ tw,
    const float* __restrict__ tb, ushort* __restrict__ aggr,
    ushort* __restrict__ hbf, float* __restrict__ lu_f) {
  int i = blockIdx.x;
  int c = threadIdx.x;
  int nid = node_ids[i];
  int did = mdst[nid];
  float d0 = mdir[nid * 2 + 0], d1 = mdir[nid * 2 + 1];
  float s  = mem_table[(size_t)nid * 256 + c];
  float dd = mem_table[(size_t)did * 256 + c];
  size_t b = (size_t)i * KP_AGGR;
  aggr[b + c]       = f2b(s * d0 + dd * d1);
  aggr[b + 256 + c] = f2b(s * d1 + dd * d0);
  hbf[(size_t)i * 256 + c] = f2b(s);
  if (c < MSGD) aggr[b + 512 + c] = f2b(mem_msg[(size_t)nid * MSGD + c]);
  if (c < 128) {
    float rt = (float)mrt[nid];
    aggr[b + 684 + c] = f2b(cosf(rt * tw[c] + tb[c]));
  }
  if (c < 20) aggr[b + 812 + c] = 0;
  if (c == 0) lu_f[i] = (float)mlu[nid];
}

// rel[e] = lu_f[src[e]] - edge_t[e]
__global__ void edge_rel(const int* __restrict__ src, const float* __restrict__ lu_f,
                         const float* __restrict__ et, float* __restrict__ rel) {
  int e = blockIdx.x * blockDim.x + threadIdx.x;
  if (e < EE) rel[e] = lu_f[src[e]] - et[e];
}

// Edge feature matrix bf16 [EE, 320] = [msg(172) | cos-te(128) | pad(20)]
__global__ void build_efeat(const float* __restrict__ emsg, const float* __restrict__ rel,
                            const float* __restrict__ tw, const float* __restrict__ tb,
                            ushort* __restrict__ efeat) {
  int e = blockIdx.x, k = threadIdx.x;  // 320 threads
  float v;
  if (k < MSGD) v = emsg[(size_t)e * MSGD + k];
  else if (k < 300) { int t = k - MSGD; v = cosf(rel[e] * tw[t] + tb[t]); }
  else v = 0.f;
  efeat[(size_t)e * KP_EDGE + k] = f2b(v);
}

// ---------------------------------------------------------------------------
// bf16 MFMA GEMM: C[M,N] = A[M,K]bf16 @ B[N,K]bf16^T + bias
// 128x128 tile, BK=32, 4 waves in 2x2, each wave 4x4 of 16x16x32 MFMAs.
// LDS chunk layout XOR-swizzled: chunk col c' holds global chunk c'^((r>>1)&3).
__global__ __launch_bounds__(256) void gemm_bf16(
    const ushort* __restrict__ A, int lda,
    const ushort* __restrict__ B, int ldb,
    const float* __restrict__ bias,
    float* __restrict__ Cf, ushort* __restrict__ Cb, int ldc, int ksteps) {
  __shared__ __attribute__((aligned(16))) ushort As[128 * 32];
  __shared__ __attribute__((aligned(16))) ushort Bs[128 * 32];
  int tid = threadIdx.x;
  int wave = tid >> 6, lane = tid & 63;
  int quad = lane >> 4, r16 = lane & 15;
  int m0 = blockIdx.x * 128, n0 = blockIdx.y * 128;
  int wm = (wave & 1) * 64, wn = (wave >> 1) * 64;

  f32x4 acc[4][4];
#pragma unroll
  for (int i = 0; i < 4; ++i)
#pragma unroll
    for (int j = 0; j < 4; ++j) acc[i][j] = (f32x4){0.f, 0.f, 0.f, 0.f};

  // staging: wave handles chunks s = wave*128 + q*64 + lane (q=0,1); 16B each
  int s0 = wave * 128 + lane;
  int r0 = s0 >> 2, c0 = (s0 & 3) ^ ((r0 >> 1) & 3);
  int s1 = s0 + 64;
  int r1 = s1 >> 2, c1 = (s1 & 3) ^ ((r1 >> 1) & 3);
  const ushort* Ag0 = A + (size_t)(m0 + r0) * lda + c0 * 8;
  const ushort* Ag1 = A + (size_t)(m0 + r1) * lda + c1 * 8;
  const ushort* Bg0 = B + (size_t)(n0 + r0) * ldb + c0 * 8;
  const ushort* Bg1 = B + (size_t)(n0 + r1) * ldb + c1 * 8;
  ushort* Al0 = As + (wave * 128) * 8;
  ushort* Al1 = As + (wave * 128 + 64) * 8;
  ushort* Bl0 = Bs + (wave * 128) * 8;
  ushort* Bl1 = Bs + (wave * 128 + 64) * 8;

  for (int t = 0; t < ksteps; ++t) {
    __builtin_amdgcn_global_load_lds(
        (const __attribute__((address_space(1))) void*)Ag0,
        (__attribute__((address_space(3))) void*)Al0, 16, 0, 0);
    __builtin_amdgcn_global_load_lds(
        (const __attribute__((address_space(1))) void*)Ag1,
        (__attribute__((address_space(3))) void*)Al1, 16, 0, 0);
    __builtin_amdgcn_global_load_lds(
        (const __attribute__((address_space(1))) void*)Bg0,
        (__attribute__((address_space(3))) void*)Bl0, 16, 0, 0);
    __builtin_amdgcn_global_load_lds(
        (const __attribute__((address_space(1))) void*)Bg1,
        (__attribute__((address_space(3))) void*)Bl1, 16, 0, 0);
    Ag0 += 32; Ag1 += 32; Bg0 += 32; Bg1 += 32;
    __syncthreads();

    bf16x8 af[4], bfr[4];
#pragma unroll
    for (int i = 0; i < 4; ++i) {
      int row = wm + i * 16 + r16;
      af[i] = *(const bf16x8*)(As + row * 32 + ((quad ^ ((row >> 1) & 3)) * 8));
    }
#pragma unroll
    for (int j = 0; j < 4; ++j) {
      int row = wn + j * 16 + r16;
      bfr[j] = *(const bf16x8*)(Bs + row * 32 + ((quad ^ ((row >> 1) & 3)) * 8));
    }
#pragma unroll
    for (int i = 0; i < 4; ++i)
#pragma unroll
      for (int j = 0; j < 4; ++j)
        acc[i][j] = __builtin_amdgcn_mfma_f32_16x16x32_bf16(af[i], bfr[j], acc[i][j], 0, 0, 0);
    __syncthreads();
  }

#pragma unroll
  for (int j = 0; j < 4; ++j) {
    int col = n0 + wn + j * 16 + r16;
    float bv = bias ? bias[col] : 0.f;
#pragma unroll
    for (int i = 0; i < 4; ++i) {
#pragma unroll
      for (int rr = 0; rr < 4; ++rr) {
        int row = m0 + wm + i * 16 + quad * 4 + rr;
        float v = acc[i][j][rr] + bv;
        if (Cf) Cf[(size_t)row * ldc + col] = v;
        else    Cb[(size_t)row * ldc + col] = f2b(v);
      }
    }
  }
}

// ---------------------------------------------------------------------------
// GRU combine -> memory (bf16)
__global__ void gru_combine(const float* __restrict__ gi, const float* __restrict__ gh,
                            const int* __restrict__ node_ids,
                            const float* __restrict__ mem_table,
                            ushort* __restrict__ membf) {
  int idx = blockIdx.x * 256 + threadIdx.x;  // NN*256
  int n = idx >> 8, c = idx & 255;
  size_t b = (size_t)n * 768;
  float ir = gi[b + c], iz = gi[b + 256 + c], in_ = gi[b + 512 + c];
  float hr = gh[b + c], hz = gh[b + 256 + c], hn = gh[b + 512 + c];
  float r = sigmoidf_(ir + hr);
  float z = sigmoidf_(iz + hz);
  float nn2 = tanhf(in_ + r * hn);
  float hv = mem_table[(size_t)node_ids[n] * 256 + c];
  membf[idx] = f2b((1.f - z) * nn2 + z * hv);
}

// z init from skip columns of qkvs; zero denom; zero max keys.
__global__ void init_attn(const float* __restrict__ qkvs, float* __restrict__ z,
                          float* __restrict__ denom, unsigned* __restrict__ maxkey) {
  int idx = blockIdx.x * 256 + threadIdx.x;  // NN*256
  int n = idx >> 8, c = idx & 255;
  z[idx] = qkvs[(size_t)n * 1024 + 768 + c];
  if (idx < NN * 2) denom[idx] = 0.f;
  if (idx < 2) maxkey[idx] = 0u;
}

// alpha[e,h] = q[dst]·(k[src]+eproj[e]) / sqrt(128); global max via atomicMax key
__global__ __launch_bounds__(256) void attn_alpha(
    const int* __restrict__ src, const int* __restrict__ dst,
    const float* __restrict__ qkvs, const ushort* __restrict__ eproj,
    float* __restrict__ alpha, unsigned* __restrict__ maxkey) {
  __shared__ float wmax[4][2];
  int wid = threadIdx.x >> 6, lane = threadIdx.x & 63;
  int e = blockIdx.x * 4 + wid;
  int sE = src[e], dE = dst[e];
  int c = lane * 4;
  float4 qv = *(const float4*)&qkvs[(size_t)dE * 1024 + c];
  float4 kv = *(const float4*)&qkvs[(size_t)sE * 1024 + 256 + c];
  ushort4 eu = *(const ushort4*)&eproj[(size_t)e * 256 + c];
  float p = qv.x * (kv.x + b2f(eu.x)) + qv.y * (kv.y + b2f(eu.y)) +
            qv.z * (kv.z + b2f(eu.z)) + qv.w * (kv.w + b2f(eu.w));
#pragma unroll
  for (int off = 16; off >= 1; off >>= 1) p += __shfl_xor(p, off);
  float a = p * 0.08838834764831845f;  // 1/sqrt(128)
  if (lane == 0)  { alpha[e * 2 + 0] = a; wmax[wid][0] = a; }
  if (lane == 32) { alpha[e * 2 + 1] = a; wmax[wid][1] = a; }
  __syncthreads();
  if (threadIdx.x < 2) {
    int hh = threadIdx.x;
    float m = fmaxf(fmaxf(wmax[0][hh], wmax[1][hh]), fmaxf(wmax[2][hh], wmax[3][hh]));
    atomicMax(maxkey + hh, fkey(m));
  }
}

// e_exp = exp(alpha - m); denom[dst,h] += e_exp
__global__ void attn_exp(const int* __restrict__ dst, float* __restrict__ alpha,
                         const unsigned* __restrict__ maxkey, float* __restrict__ denom) {
  int idx = blockIdx.x * blockDim.x + threadIdx.x;  // EE*2
  if (idx >= EE * 2) return;
  int e = idx >> 1, hh = idx & 1;
  float m = funkey(maxkey[hh]);
  float v = expf(alpha[idx] - m);
  alpha[idx] = v;
  atomicAdd(&denom[dst[e] * 2 + hh], v);
}

// z[dst] += (v[src]+eproj[e]) * alpha_norm
__global__ __launch_bounds__(256) void attn_agg(
    const int* __restrict__ src, const int* __restrict__ dst,
    const float* __restrict__ qkvs, const ushort* __restrict__ eproj,
    const float* __restrict__ alpha, const float* __restrict__ denom,
    float* __restrict__ z) {
  int wid = threadIdx.x >> 6, lane = threadIdx.x & 63;
  int e = blockIdx.x * 4 + wid;
  int sE = src[e], dE = dst[e];
  float c0 = alpha[e * 2 + 0] / (denom[dE * 2 + 0] + 1e-16f);
  float c1 = alpha[e * 2 + 1] / (denom[dE * 2 + 1] + 1e-16f);
  int c = lane * 4;
  float coef = (c < 128) ? c0 : c1;
  float4 vv = *(const float4*)&qkvs[(size_t)sE * 1024 + 512 + c];
  ushort4 eu = *(const ushort4*)&eproj[(size_t)e * 256 + c];
  float* zp = &z[(size_t)dE * 256 + c];
  atomicAdd(zp + 0, (vv.x + b2f(eu.x)) * coef);
  atomicAdd(zp + 1, (vv.y + b2f(eu.y)) * coef);
  atomicAdd(zp + 2, (vv.z + b2f(eu.z)) * coef);
  atomicAdd(zp + 3, (vv.w + b2f(eu.w)) * coef);
}

// ---------------------------------------------------------------------------
// LinkPredictor
__global__ __launch_bounds__(256) void link_pred_k(
    const int* __restrict__ node_idx, const float* __restrict__ z,
    const float* __restrict__ lpwT, const float* __restrict__ lp_hb,
    const float* __restrict__ lp_fw, const float* __restrict__ lp_fb,
    float* __restrict__ out) {
  __shared__ float cat[16][512];
  __shared__ float red[16][4];
  __shared__ int i0s[16];
  int tid = threadIdx.x;
#pragma unroll
  for (int rr = 0; rr < 16; ++rr) {
    int row = blockIdx.x * 16 + rr;     // 0..8191
    int b = row & (BB - 1);
    int neg = row >= BB;
    int i0 = node_idx[b];
    int i1 = node_idx[(neg ? 2 : 1) * BB + b];
    if (tid == 0) i0s[rr] = i0;
    cat[rr][tid]       = z[(size_t)i0 * 256 + tid];
    cat[rr][256 + tid] = z[(size_t)i1 * 256 + tid];
  }
  __syncthreads();
  float acc[16];
#pragma unroll
  for (int rr = 0; rr < 16; ++rr) acc[rr] = 0.f;
  for (int k = 0; k < 512; ++k) {
    float w = lpwT[k * 256 + tid];
#pragma unroll
    for (int rr = 0; rr < 16; ++rr) acc[rr] += w * cat[rr][k];
  }
  float hb = lp_hb[tid], fw = lp_fw[tid];
  int wid = tid >> 6, lane = tid & 63;
#pragma unroll
  for (int rr = 0; rr < 16; ++rr) {
    float v = fmaxf(acc[rr] + hb, 0.f) * fw;
#pragma unroll
    for (int off = 32; off >= 1; off >>= 1) v += __shfl_xor(v, off);
    if (lane == 0) red[rr][wid] = v;
  }
  __syncthreads();
  if (tid < 16) {
    int rr = tid;
    float dot = red[rr][0] + red[rr][1] + red[rr][2] + red[rr][3] + lp_fb[0];
    float mask = (i0s[rr] < NN - 1) ? 1.f : 0.f;
    out[blockIdx.x * 16 + rr] = sigmoidf_(dot * mask);
  }
}

// ---------------------------------------------------------------------------
extern "C" void kernel_launch(void* const* d_in, const int* in_sizes, int n_in,
                              void* d_out, int out_size, void* d_ws, size_t ws_size,
                              hipStream_t stream) {
  const int* node_ids = (const int*)d_in[0];
  const int* node_idx = (const int*)d_in[1];
  const int* edge_src = (const int*)d_in[2];
  const int* edge_dst = edge_src + EE;
  const int* mlu = (const int*)d_in[3];
  const int* mrt = (const int*)d_in[4];
  const int* mdst = (const int*)d_in[5];
  const float* edge_t = (const float*)d_in[6];
  const float* edge_msg = (const float*)d_in[7];
  const float* mem_table = (const float*)d_in[8];
  const float* mem_msg = (const float*)d_in[9];
  const float* mem_dir = (const float*)d_in[10];
  const float* te_mem_w = (const float*)d_in[11];
  const float* te_mem_b = (const float*)d_in[12];
  const float* gru_w_ih = (const float*)d_in[13];
  const float* gru_w_hh = (const float*)d_in[14];
  const float* gru_b_ih = (const float*)d_in[15];
  const float* gru_b_hh = (const float*)d_in[16];
  const float* te_gnn_w = (const float*)d_in[17];
  const float* te_gnn_b = (const float*)d_in[18];
  const float* Wq = (const float*)d_in[19];  const float* bq = (const float*)d_in[20];
  const float* Wk = (const float*)d_in[21];  const float* bk = (const float*)d_in[22];
  const float* Wv = (const float*)d_in[23];  const float* bv = (const float*)d_in[24];
  const float* We = (const float*)d_in[25];
  const float* Wskip = (const float*)d_in[26]; const float* bskip = (const float*)d_in[27];
  const float* lp_hw = (const float*)d_in[28]; const float* lp_hb = (const float*)d_in[29];
  const float* lp_fw = (const float*)d_in[30]; const float* lp_fb = (const float*)d_in[31];

  char* base = (char*)d_ws;
  size_t off = 0;
  auto take = [&](size_t n) { void* p = base + off; off += (n + 255) & ~(size_t)255; return p; };

  // R1 pool (aggr/h/gi/gh) -> later aliased by eproj
  ushort* aggr  = (ushort*)take((size_t)NN * KP_AGGR * 2);   // 27.3 MB
  ushort* hbf   = (ushort*)take((size_t)NN * 256 * 2);       // 8.4 MB
  float*  gi    = (float*) take((size_t)NN * 768 * 4);       // 50.3 MB
  float*  gh    = (float*) take((size_t)NN * 768 * 4);       // 50.3 MB
  ushort* eproj = aggr;                                      // alias (67.1 MB pool)
  ushort* efeat = (ushort*)take((size_t)EE * KP_EDGE * 2);   // 83.9 MB
  ushort* membf = (ushort*)take((size_t)NN * 256 * 2);       // 8.4 MB
  float*  qkvs  = (float*) take((size_t)NN * 1024 * 4);      // 67.1 MB
  float*  zbuf  = (float*) take((size_t)NN * 256 * 4);       // 16.8 MB
  float*  alpha = (float*) take((size_t)EE * 2 * 4);
  float*  denom = (float*) take((size_t)NN * 2 * 4);
  unsigned* maxkey = (unsigned*)take(256);
  float*  lu_f  = (float*) take((size_t)NN * 4);
  float*  rel   = (float*) take((size_t)EE * 4);
  ushort* wihb  = (ushort*)take((size_t)768 * KP_AGGR * 2);
  ushort* whhb  = (ushort*)take((size_t)768 * 256 * 2);
  ushort* wcatb = (ushort*)take((size_t)1024 * 256 * 2);
  float*  bcat  = (float*) take(1024 * 4);
  ushort* web   = (ushort*)take((size_t)256 * KP_EDGE * 2);
  float*  lpwT  = (float*) take((size_t)512 * 256 * 4);

  // weight packing
  pack_gru<<<768, 256, 0, stream>>>(gru_w_ih, gru_w_hh, wihb, whhb);
  pack_attn<<<1024, 256, 0, stream>>>(Wq, bq, Wk, bk, Wv, bv, Wskip, bskip, We,
                                      wcatb, bcat, web);
  pack_lp<<<512, 256, 0, stream>>>(lp_hw, lpwT);

  // node features + edge features
  build_node<<<NN, 256, 0, stream>>>(node_ids, mlu, mrt, mdst, mem_table, mem_msg,
                                     mem_dir, te_mem_w, te_mem_b, aggr, hbf, lu_f);
  edge_rel<<<EE / 256, 256, 0, stream>>>(edge_src, lu_f, edge_t, rel);
  build_efeat<<<EE, 320, 0, stream>>>(edge_msg, rel, te_gnn_w, te_gnn_b, efeat);

  // GRU gates
  dim3 g1(NN / 128, 768 / 128);
  gemm_bf16<<<g1, 256, 0, stream>>>(aggr, KP_AGGR, wihb, KP_AGGR, gru_b_ih,
                                    gi, nullptr, 768, KP_AGGR / 32);
  gemm_bf16<<<g1, 256, 0, stream>>>(hbf, 256, whhb, 256, gru_b_hh,
                                    gh, nullptr, 768, 256 / 32);
  gru_combine<<<NN, 256, 0, stream>>>(gi, gh, node_ids, mem_table, membf);

  // fused q/k/v/skip
  dim3 g2(NN / 128, 1024 / 128);
  gemm_bf16<<<g2, 256, 0, stream>>>(membf, 256, wcatb, 256, bcat,
                                    qkvs, nullptr, 1024, 256 / 32);
  init_attn<<<NN, 256, 0, stream>>>(qkvs, zbuf, denom, maxkey);

  // edge projection (bf16 out, aliases R1 — gi/gh dead after gru_combine)
  dim3 g3(EE / 128, 256 / 128);
  gemm_bf16<<<g3, 256, 0, stream>>>(efeat, KP_EDGE, web, KP_EDGE, nullptr,
                                    nullptr, eproj, 256, KP_EDGE / 32);

  // attention
  attn_alpha<<<EE / 4, 256, 0, stream>>>(edge_src, edge_dst, qkvs, eproj, alpha, maxkey);
  attn_exp<<<(EE * 2) / 256, 256, 0, stream>>>(edge_dst, alpha, maxkey, denom);
  attn_agg<<<EE / 4, 256, 0, stream>>>(edge_src, edge_dst, qkvs, eproj, alpha, denom, zbuf);

  // link predictor
  link_pred_k<<<(2 * BB) / 16, 256, 0, stream>>>(node_idx, zbuf, lpwT, lp_hb,
                                                 lp_fw, lp_fb, (float*)d_out);
}

// Round 4
// 1118.370 us; speedup vs baseline: 2.3390x; 1.3387x over previous
//
#include <hip/hip_runtime.h>
#include <hip/hip_bf16.h>
#include <math.h>

// Problem constants
#define NN   16384   // batch subgraph nodes
#define EE   131072  // edges
#define BB   4096    // events
#define MSGD 172
#define KP_AGGR 832  // 812 padded to 26*32
#define KP_EDGE 320  // 300 padded to 10*32

typedef __attribute__((ext_vector_type(8))) short bf16x8;
typedef __attribute__((ext_vector_type(4))) float f32x4;

__device__ __forceinline__ ushort f2b(float x) {
  unsigned u = __float_as_uint(x);
  return (ushort)((u + 0x7fffu + ((u >> 16) & 1u)) >> 16);  // RNE
}
__device__ __forceinline__ float b2f(ushort b) {
  return __uint_as_float(((unsigned)b) << 16);
}
__device__ __forceinline__ unsigned fkey(float x) {
  unsigned b = __float_as_uint(x);
  return (b & 0x80000000u) ? ~b : (b | 0x80000000u);
}
__device__ __forceinline__ float funkey(unsigned k) {
  unsigned b = (k & 0x80000000u) ? (k & 0x7fffffffu) : ~k;
  return __uint_as_float(b);
}
__device__ __forceinline__ float sigmoidf_(float x) { return 1.f / (1.f + expf(-x)); }

// ---------------------------------------------------------------------------
// Weight packing (fp32 -> bf16, padded)
__global__ void pack_gru(const float* __restrict__ w_ih, const float* __restrict__ w_hh,
                         ushort* __restrict__ wihb, ushort* __restrict__ whhb) {
  int n = blockIdx.x;     // 0..767
  int c = threadIdx.x;    // 0..255
  for (int k = c; k < KP_AGGR; k += 256)
    wihb[(size_t)n * KP_AGGR + k] = (k < 812) ? f2b(w_ih[(size_t)n * 812 + k]) : (ushort)0;
  whhb[(size_t)n * 256 + c] = f2b(w_hh[(size_t)n * 256 + c]);
}

__global__ void pack_attn(const float* __restrict__ Wq, const float* __restrict__ bq,
                          const float* __restrict__ Wk, const float* __restrict__ bk,
                          const float* __restrict__ Wv, const float* __restrict__ bv,
                          const float* __restrict__ Ws, const float* __restrict__ bs,
                          const float* __restrict__ We,
                          ushort* __restrict__ wcatb, float* __restrict__ bcat,
                          ushort* __restrict__ web) {
  int n = blockIdx.x;     // 0..1023
  int c = threadIdx.x;    // 0..255
  const float* Wsel; const float* bsel; int r;
  if (n < 256)      { Wsel = Wq; bsel = bq; r = n; }
  else if (n < 512) { Wsel = Wk; bsel = bk; r = n - 256; }
  else if (n < 768) { Wsel = Wv; bsel = bv; r = n - 512; }
  else              { Wsel = Ws; bsel = bs; r = n - 768; }
  wcatb[(size_t)n * 256 + c] = f2b(Wsel[(size_t)r * 256 + c]);
  if (c == 0) bcat[n] = bsel[r];
  if (n < 256) {
    for (int k = c; k < KP_EDGE; k += 256)
      web[(size_t)n * KP_EDGE + k] = (k < 300) ? f2b(We[(size_t)n * 300 + k]) : (ushort)0;
  }
}

__global__ void pack_lp(const float* __restrict__ lp_hw, float* __restrict__ lpwT) {
  int k = blockIdx.x;     // 0..511
  int t = threadIdx.x;    // 0..255
  lpwT[(size_t)k * 256 + t] = lp_hw[(size_t)t * 512 + k];
}

// ---------------------------------------------------------------------------
// Per-node: aggr bf16 [NN, 832], h bf16 [NN,256], lu_f [NN]
__global__ __launch_bounds__(256) void build_node(
    const int* __restrict__ node_ids, const int* __restrict__ mlu,
    const int* __restrict__ mrt, const int* __restrict__ mdst,
    const float* __restrict__ mem_table, const float* __restrict__ mem_msg,
    const float* __restrict__ mdir, const float* __restrict__ tw,
    const float* __restrict__ tb, ushort* __restrict__ aggr,
    ushort* __restrict__ hbf, float* __restrict__ lu_f) {
  int i = blockIdx.x;
  int c = threadIdx.x;
  int nid = node_ids[i];
  int did = mdst[nid];
  float d0 = mdir[nid * 2 + 0], d1 = mdir[nid * 2 + 1];
  float s  = mem_table[(size_t)nid * 256 + c];
  float dd = mem_table[(size_t)did * 256 + c];
  size_t b = (size_t)i * KP_AGGR;
  aggr[b + c]       = f2b(s * d0 + dd * d1);
  aggr[b + 256 + c] = f2b(s * d1 + dd * d0);
  hbf[(size_t)i * 256 + c] = f2b(s);
  if (c < MSGD) aggr[b + 512 + c] = f2b(mem_msg[(size_t)nid * MSGD + c]);
  if (c < 128) {
    float rt = (float)mrt[nid];
    aggr[b + 684 + c] = f2b(cosf(rt * tw[c] + tb[c]));
  }
  if (c < 20) aggr[b + 812 + c] = 0;
  if (c == 0) lu_f[i] = (float)mlu[nid];
}

// rel[e] = lu_f[src[e]] - edge_t[e]
__global__ void edge_rel(const int* __restrict__ src, const float* __restrict__ lu_f,
                         const float* __restrict__ et, float* __restrict__ rel) {
  int e = blockIdx.x * blockDim.x + threadIdx.x;
  if (e < EE) rel[e] = lu_f[src[e]] - et[e];
}

// Edge feature matrix bf16 [EE, 320] = [msg(172) | cos-te(128) | pad(20)]
__global__ void build_efeat(const float* __restrict__ emsg, const float* __restrict__ rel,
                            const float* __restrict__ tw, const float* __restrict__ tb,
                            ushort* __restrict__ efeat) {
  int e = blockIdx.x, k = threadIdx.x;  // 320 threads
  float v;
  if (k < MSGD) v = emsg[(size_t)e * MSGD + k];
  else if (k < 300) { int t = k - MSGD; v = cosf(rel[e] * tw[t] + tb[t]); }
  else v = 0.f;
  efeat[(size_t)e * KP_EDGE + k] = f2b(v);
}

// ---------------------------------------------------------------------------
// bf16 MFMA GEMM: C[M,N] = A[M,K]bf16 @ B[N,K]bf16^T + bias
__global__ __launch_bounds__(256) void gemm_bf16(
    const ushort* __restrict__ A, int lda,
    const ushort* __restrict__ B, int ldb,
    const float* __restrict__ bias,
    float* __restrict__ Cf, ushort* __restrict__ Cb, int ldc, int ksteps) {
  __shared__ __attribute__((aligned(16))) ushort As[128 * 32];
  __shared__ __attribute__((aligned(16))) ushort Bs[128 * 32];
  int tid = threadIdx.x;
  int wave = tid >> 6, lane = tid & 63;
  int quad = lane >> 4, r16 = lane & 15;
  int m0 = blockIdx.x * 128, n0 = blockIdx.y * 128;
  int wm = (wave & 1) * 64, wn = (wave >> 1) * 64;

  f32x4 acc[4][4];
#pragma unroll
  for (int i = 0; i < 4; ++i)
#pragma unroll
    for (int j = 0; j < 4; ++j) acc[i][j] = (f32x4){0.f, 0.f, 0.f, 0.f};

  int s0 = wave * 128 + lane;
  int r0 = s0 >> 2, c0 = (s0 & 3) ^ ((r0 >> 1) & 3);
  int s1 = s0 + 64;
  int r1 = s1 >> 2, c1 = (s1 & 3) ^ ((r1 >> 1) & 3);
  const ushort* Ag0 = A + (size_t)(m0 + r0) * lda + c0 * 8;
  const ushort* Ag1 = A + (size_t)(m0 + r1) * lda + c1 * 8;
  const ushort* Bg0 = B + (size_t)(n0 + r0) * ldb + c0 * 8;
  const ushort* Bg1 = B + (size_t)(n0 + r1) * ldb + c1 * 8;
  ushort* Al0 = As + (wave * 128) * 8;
  ushort* Al1 = As + (wave * 128 + 64) * 8;
  ushort* Bl0 = Bs + (wave * 128) * 8;
  ushort* Bl1 = Bs + (wave * 128 + 64) * 8;

  for (int t = 0; t < ksteps; ++t) {
    __builtin_amdgcn_global_load_lds(
        (const __attribute__((address_space(1))) void*)Ag0,
        (__attribute__((address_space(3))) void*)Al0, 16, 0, 0);
    __builtin_amdgcn_global_load_lds(
        (const __attribute__((address_space(1))) void*)Ag1,
        (__attribute__((address_space(3))) void*)Al1, 16, 0, 0);
    __builtin_amdgcn_global_load_lds(
        (const __attribute__((address_space(1))) void*)Bg0,
        (__attribute__((address_space(3))) void*)Bl0, 16, 0, 0);
    __builtin_amdgcn_global_load_lds(
        (const __attribute__((address_space(1))) void*)Bg1,
        (__attribute__((address_space(3))) void*)Bl1, 16, 0, 0);
    Ag0 += 32; Ag1 += 32; Bg0 += 32; Bg1 += 32;
    __syncthreads();

    bf16x8 af[4], bfr[4];
#pragma unroll
    for (int i = 0; i < 4; ++i) {
      int row = wm + i * 16 + r16;
      af[i] = *(const bf16x8*)(As + row * 32 + ((quad ^ ((row >> 1) & 3)) * 8));
    }
#pragma unroll
    for (int j = 0; j < 4; ++j) {
      int row = wn + j * 16 + r16;
      bfr[j] = *(const bf16x8*)(Bs + row * 32 + ((quad ^ ((row >> 1) & 3)) * 8));
    }
#pragma unroll
    for (int i = 0; i < 4; ++i)
#pragma unroll
      for (int j = 0; j < 4; ++j)
        acc[i][j] = __builtin_amdgcn_mfma_f32_16x16x32_bf16(af[i], bfr[j], acc[i][j], 0, 0, 0);
    __syncthreads();
  }

#pragma unroll
  for (int j = 0; j < 4; ++j) {
    int col = n0 + wn + j * 16 + r16;
    float bv = bias ? bias[col] : 0.f;
#pragma unroll
    for (int i = 0; i < 4; ++i) {
#pragma unroll
      for (int rr = 0; rr < 4; ++rr) {
        int row = m0 + wm + i * 16 + quad * 4 + rr;
        float v = acc[i][j][rr] + bv;
        if (Cf) Cf[(size_t)row * ldc + col] = v;
        else    Cb[(size_t)row * ldc + col] = f2b(v);
      }
    }
  }
}

// ---------------------------------------------------------------------------
// GRU combine -> memory (bf16)
__global__ void gru_combine(const float* __restrict__ gi, const float* __restrict__ gh,
                            const int* __restrict__ node_ids,
                            const float* __restrict__ mem_table,
                            ushort* __restrict__ membf) {
  int idx = blockIdx.x * 256 + threadIdx.x;  // NN*256
  int n = idx >> 8, c = idx & 255;
  size_t b = (size_t)n * 768;
  float ir = gi[b + c], iz = gi[b + 256 + c], in_ = gi[b + 512 + c];
  float hr = gh[b + c], hz = gh[b + 256 + c], hn = gh[b + 512 + c];
  float r = sigmoidf_(ir + hr);
  float z = sigmoidf_(iz + hz);
  float nn2 = tanhf(in_ + r * hn);
  float hv = mem_table[(size_t)node_ids[n] * 256 + c];
  membf[idx] = f2b((1.f - z) * nn2 + z * hv);
}

// ---------------------------------------------------------------------------
// CSR build: zero counters, histogram, single-block scan, scatter
__global__ void attn_init(int* __restrict__ cnt, unsigned* __restrict__ maxkey) {
  int i = blockIdx.x * 256 + threadIdx.x;
  if (i < NN) cnt[i] = 0;
  if (i < 2) maxkey[i] = 0u;
}

__global__ void csr_hist(const int* __restrict__ dst, int* __restrict__ cnt) {
  int e = blockIdx.x * 256 + threadIdx.x;
  if (e < EE) atomicAdd(&cnt[dst[e]], 1);
}

__global__ __launch_bounds__(256) void csr_scan(const int* __restrict__ cnt,
                                                int* __restrict__ rowptr,
                                                int* __restrict__ cursor) {
  __shared__ int tsum[256];
  int t = threadIdx.x;
  int base = t * 64;
  int s = 0;
  for (int i = 0; i < 64; ++i) s += cnt[base + i];
  tsum[t] = s;
  __syncthreads();
  if (t == 0) {
    int run = 0;
    for (int i = 0; i < 256; ++i) { int v = tsum[i]; tsum[i] = run; run += v; }
    rowptr[NN] = run;  // == EE
  }
  __syncthreads();
  int run = tsum[t];
  for (int i = 0; i < 64; ++i) {
    rowptr[base + i] = run;
    cursor[base + i] = run;
    run += cnt[base + i];
  }
}

__global__ void csr_scatter(const int* __restrict__ dst, int* __restrict__ cursor,
                            int* __restrict__ elist) {
  int e = blockIdx.x * 256 + threadIdx.x;
  if (e < EE) {
    int p = atomicAdd(&cursor[dst[e]], 1);
    elist[p] = e;
  }
}

// ---------------------------------------------------------------------------
// alpha[e,h] = q[dst]·(k[src]+eproj[e]) / sqrt(128); global max via atomicMax key
__global__ __launch_bounds__(256) void attn_alpha(
    const int* __restrict__ src, const int* __restrict__ dst,
    const float* __restrict__ qkvs, const ushort* __restrict__ eproj,
    float* __restrict__ alpha, unsigned* __restrict__ maxkey) {
  __shared__ float wmax[4][2];
  int wid = threadIdx.x >> 6, lane = threadIdx.x & 63;
  int e = blockIdx.x * 4 + wid;
  int sE = src[e], dE = dst[e];
  int c = lane * 4;
  float4 qv = *(const float4*)&qkvs[(size_t)dE * 1024 + c];
  float4 kv = *(const float4*)&qkvs[(size_t)sE * 1024 + 256 + c];
  ushort4 eu = *(const ushort4*)&eproj[(size_t)e * 256 + c];
  float p = qv.x * (kv.x + b2f(eu.x)) + qv.y * (kv.y + b2f(eu.y)) +
            qv.z * (kv.z + b2f(eu.z)) + qv.w * (kv.w + b2f(eu.w));
#pragma unroll
  for (int off = 16; off >= 1; off >>= 1) p += __shfl_xor(p, off);
  float a = p * 0.08838834764831845f;  // 1/sqrt(128)
  if (lane == 0)  { alpha[e * 2 + 0] = a; wmax[wid][0] = a; }
  if (lane == 32) { alpha[e * 2 + 1] = a; wmax[wid][1] = a; }
  __syncthreads();
  if (threadIdx.x < 2) {
    int hh = threadIdx.x;
    float m = fmaxf(fmaxf(wmax[0][hh], wmax[1][hh]), fmaxf(wmax[2][hh], wmax[3][hh]));
    atomicMax(maxkey + hh, fkey(m));
  }
}

// ---------------------------------------------------------------------------
// Fused softmax+aggregate: one wave per dst node, CSR edge list, no atomics.
// z[i] = skip_i + (sum_e exp(alpha_e - m) * (v[src_e]+eproj_e)) / (sum_e exp + 1e-16)
__global__ __launch_bounds__(256) void attn_fused(
    const int* __restrict__ src, const int* __restrict__ elist,
    const int* __restrict__ rowptr, const float* __restrict__ qkvs,
    const ushort* __restrict__ eproj, const float* __restrict__ alpha,
    const unsigned* __restrict__ maxkey, float* __restrict__ z) {
  int wid = threadIdx.x >> 6, lane = threadIdx.x & 63;
  int i = blockIdx.x * 4 + wid;
  int beg = rowptr[i], end = rowptr[i + 1];
  float m0 = funkey(maxkey[0]), m1 = funkey(maxkey[1]);
  int c = lane * 4;
  float4 acc = {0.f, 0.f, 0.f, 0.f};
  float den0 = 0.f, den1 = 0.f;
  for (int p = beg; p < end; ++p) {
    int e = elist[p];
    int sE = src[e];
    float a0 = expf(alpha[e * 2 + 0] - m0);
    float a1 = expf(alpha[e * 2 + 1] - m1);
    den0 += a0; den1 += a1;
    float w = (c < 128) ? a0 : a1;
    float4 vv = *(const float4*)&qkvs[(size_t)sE * 1024 + 512 + c];
    ushort4 eu = *(const ushort4*)&eproj[(size_t)e * 256 + c];
    acc.x += (vv.x + b2f(eu.x)) * w;
    acc.y += (vv.y + b2f(eu.y)) * w;
    acc.z += (vv.z + b2f(eu.z)) * w;
    acc.w += (vv.w + b2f(eu.w)) * w;
  }
  float den = (c < 128) ? den0 : den1;
  float inv = 1.f / (den + 1e-16f);
  float4 sk = *(const float4*)&qkvs[(size_t)i * 1024 + 768 + c];
  float4 o = {sk.x + acc.x * inv, sk.y + acc.y * inv,
              sk.z + acc.z * inv, sk.w + acc.w * inv};
  *(float4*)&z[(size_t)i * 256 + c] = o;
}

// ---------------------------------------------------------------------------
// LinkPredictor
__global__ __launch_bounds__(256) void link_pred_k(
    const int* __restrict__ node_idx, const float* __restrict__ z,
    const float* __restrict__ lpwT, const float* __restrict__ lp_hb,
    const float* __restrict__ lp_fw, const float* __restrict__ lp_fb,
    float* __restrict__ out) {
  __shared__ float cat[16][512];
  __shared__ float red[16][4];
  __shared__ int i0s[16];
  int tid = threadIdx.x;
#pragma unroll
  for (int rr = 0; rr < 16; ++rr) {
    int row = blockIdx.x * 16 + rr;     // 0..8191
    int b = row & (BB - 1);
    int neg = row >= BB;
    int i0 = node_idx[b];
    int i1 = node_idx[(neg ? 2 : 1) * BB + b];
    if (tid == 0) i0s[rr] = i0;
    cat[rr][tid]       = z[(size_t)i0 * 256 + tid];
    cat[rr][256 + tid] = z[(size_t)i1 * 256 + tid];
  }
  __syncthreads();
  float acc[16];
#pragma unroll
  for (int rr = 0; rr < 16; ++rr) acc[rr] = 0.f;
  for (int k = 0; k < 512; ++k) {
    float w = lpwT[k * 256 + tid];
#pragma unroll
    for (int rr = 0; rr < 16; ++rr) acc[rr] += w * cat[rr][k];
  }
  float hb = lp_hb[tid], fw = lp_fw[tid];
  int wid = tid >> 6, lane = tid & 63;
#pragma unroll
  for (int rr = 0; rr < 16; ++rr) {
    float v = fmaxf(acc[rr] + hb, 0.f) * fw;
#pragma unroll
    for (int off = 32; off >= 1; off >>= 1) v += __shfl_xor(v, off);
    if (lane == 0) red[rr][wid] = v;
  }
  __syncthreads();
  if (tid < 16) {
    int rr = tid;
    float dot = red[rr][0] + red[rr][1] + red[rr][2] + red[rr][3] + lp_fb[0];
    float mask = (i0s[rr] < NN - 1) ? 1.f : 0.f;
    out[blockIdx.x * 16 + rr] = sigmoidf_(dot * mask);
  }
}

// ---------------------------------------------------------------------------
extern "C" void kernel_launch(void* const* d_in, const int* in_sizes, int n_in,
                              void* d_out, int out_size, void* d_ws, size_t ws_size,
                              hipStream_t stream) {
  const int* node_ids = (const int*)d_in[0];
  const int* node_idx = (const int*)d_in[1];
  const int* edge_src = (const int*)d_in[2];
  const int* edge_dst = edge_src + EE;
  const int* mlu = (const int*)d_in[3];
  const int* mrt = (const int*)d_in[4];
  const int* mdst = (const int*)d_in[5];
  const float* edge_t = (const float*)d_in[6];
  const float* edge_msg = (const float*)d_in[7];
  const float* mem_table = (const float*)d_in[8];
  const float* mem_msg = (const float*)d_in[9];
  const float* mem_dir = (const float*)d_in[10];
  const float* te_mem_w = (const float*)d_in[11];
  const float* te_mem_b = (const float*)d_in[12];
  const float* gru_w_ih = (const float*)d_in[13];
  const float* gru_w_hh = (const float*)d_in[14];
  const float* gru_b_ih = (const float*)d_in[15];
  const float* gru_b_hh = (const float*)d_in[16];
  const float* te_gnn_w = (const float*)d_in[17];
  const float* te_gnn_b = (const float*)d_in[18];
  const float* Wq = (const float*)d_in[19];  const float* bq = (const float*)d_in[20];
  const float* Wk = (const float*)d_in[21];  const float* bk = (const float*)d_in[22];
  const float* Wv = (const float*)d_in[23];  const float* bv = (const float*)d_in[24];
  const float* We = (const float*)d_in[25];
  const float* Wskip = (const float*)d_in[26]; const float* bskip = (const float*)d_in[27];
  const float* lp_hw = (const float*)d_in[28]; const float* lp_hb = (const float*)d_in[29];
  const float* lp_fw = (const float*)d_in[30]; const float* lp_fb = (const float*)d_in[31];

  char* base = (char*)d_ws;
  size_t off = 0;
  auto take = [&](size_t n) { void* p = base + off; off += (n + 255) & ~(size_t)255; return p; };

  // R1 pool (aggr/h/gi/gh) -> later aliased by eproj
  ushort* aggr  = (ushort*)take((size_t)NN * KP_AGGR * 2);   // 27.3 MB
  ushort* hbf   = (ushort*)take((size_t)NN * 256 * 2);       // 8.4 MB
  float*  gi    = (float*) take((size_t)NN * 768 * 4);       // 50.3 MB
  float*  gh    = (float*) take((size_t)NN * 768 * 4);       // 50.3 MB
  ushort* eproj = aggr;                                      // alias (67.1 MB pool)
  ushort* efeat = (ushort*)take((size_t)EE * KP_EDGE * 2);   // 83.9 MB
  ushort* membf = (ushort*)take((size_t)NN * 256 * 2);       // 8.4 MB
  float*  qkvs  = (float*) take((size_t)NN * 1024 * 4);      // 67.1 MB
  float*  zbuf  = (float*) take((size_t)NN * 256 * 4);       // 16.8 MB
  float*  alpha = (float*) take((size_t)EE * 2 * 4);
  unsigned* maxkey = (unsigned*)take(256);
  float*  lu_f  = (float*) take((size_t)NN * 4);
  float*  rel   = (float*) take((size_t)EE * 4);
  int*    cnt   = (int*)   take((size_t)NN * 4);
  int*    rowptr= (int*)   take((size_t)(NN + 1) * 4);
  int*    cursor= (int*)   take((size_t)NN * 4);
  int*    elist = (int*)   take((size_t)EE * 4);
  ushort* wihb  = (ushort*)take((size_t)768 * KP_AGGR * 2);
  ushort* whhb  = (ushort*)take((size_t)768 * 256 * 2);
  ushort* wcatb = (ushort*)take((size_t)1024 * 256 * 2);
  float*  bcat  = (float*) take(1024 * 4);
  ushort* web   = (ushort*)take((size_t)256 * KP_EDGE * 2);
  float*  lpwT  = (float*) take((size_t)512 * 256 * 4);

  // weight packing
  pack_gru<<<768, 256, 0, stream>>>(gru_w_ih, gru_w_hh, wihb, whhb);
  pack_attn<<<1024, 256, 0, stream>>>(Wq, bq, Wk, bk, Wv, bv, Wskip, bskip, We,
                                      wcatb, bcat, web);
  pack_lp<<<512, 256, 0, stream>>>(lp_hw, lpwT);

  // CSR build (independent of feature pipeline)
  attn_init<<<NN / 256, 256, 0, stream>>>(cnt, maxkey);
  csr_hist<<<EE / 256, 256, 0, stream>>>(edge_dst, cnt);
  csr_scan<<<1, 256, 0, stream>>>(cnt, rowptr, cursor);
  csr_scatter<<<EE / 256, 256, 0, stream>>>(edge_dst, cursor, elist);

  // node features + edge features
  build_node<<<NN, 256, 0, stream>>>(node_ids, mlu, mrt, mdst, mem_table, mem_msg,
                                     mem_dir, te_mem_w, te_mem_b, aggr, hbf, lu_f);
  edge_rel<<<EE / 256, 256, 0, stream>>>(edge_src, lu_f, edge_t, rel);
  build_efeat<<<EE, 320, 0, stream>>>(edge_msg, rel, te_gnn_w, te_gnn_b, efeat);

  // GRU gates
  dim3 g1(NN / 128, 768 / 128);
  gemm_bf16<<<g1, 256, 0, stream>>>(aggr, KP_AGGR, wihb, KP_AGGR, gru_b_ih,
                                    gi, nullptr, 768, KP_AGGR / 32);
  gemm_bf16<<<g1, 256, 0, stream>>>(hbf, 256, whhb, 256, gru_b_hh,
                                    gh, nullptr, 768, 256 / 32);
  gru_combine<<<NN, 256, 0, stream>>>(gi, gh, node_ids, mem_table, membf);

  // fused q/k/v/skip
  dim3 g2(NN / 128, 1024 / 128);
  gemm_bf16<<<g2, 256, 0, stream>>>(membf, 256, wcatb, 256, bcat,
                                    qkvs, nullptr, 1024, 256 / 32);

  // edge projection (bf16 out, aliases R1 — gi/gh dead after gru_combine)
  dim3 g3(EE / 128, 256 / 128);
  gemm_bf16<<<g3, 256, 0, stream>>>(efeat, KP_EDGE, web, KP_EDGE, nullptr,
                                    nullptr, eproj, 256, KP_EDGE / 32);

  // attention
  attn_alpha<<<EE / 4, 256, 0, stream>>>(edge_src, edge_dst, qkvs, eproj, alpha, maxkey);
  attn_fused<<<NN / 4, 256, 0, stream>>>(edge_src, elist, rowptr, qkvs, eproj,
                                         alpha, maxkey, zbuf);

  // link predictor
  link_pred_k<<<(2 * BB) / 16, 256, 0, stream>>>(node_idx, zbuf, lpwT, lp_hb,
                                                 lp_fw, lp_fb, (float*)d_out);
}